// Round 1
// baseline (23.255 us; speedup 1.0000x reference)
//
#include <hip/hip_runtime.h>

#define N_DET 1024
#define N_TRK 1024
#define DD 128
#define RR 3

// ---------------------------------------------------------------------------
// Kernel A: fused linears + W_rel row-sum reduction
//   obj      = det @ W_det + b_det        -> d_ws
//   track_nb = det @ W_trk + b_trk        -> d_out (second output)
//   wsum[r]  = sum_d W_rel[r][d], bsum = sum_d b_rel[d] -> d_ws tail (block 0)
// ---------------------------------------------------------------------------
__global__ __launch_bounds__(128) void linears_kernel(
    const float* __restrict__ det,
    const float* __restrict__ Wd, const float* __restrict__ bd,
    const float* __restrict__ Wt, const float* __restrict__ bt,
    const float* __restrict__ Wr, const float* __restrict__ br,
    float* __restrict__ obj, float* __restrict__ trk_nb,
    float* __restrict__ wsum)
{
    const int tid  = threadIdx.x;          // output column d (0..127)
    const int row0 = blockIdx.x * 8;

    __shared__ float det_s[8][DD];
    #pragma unroll
    for (int r = 0; r < 8; ++r)
        det_s[r][tid] = det[(row0 + r) * DD + tid];
    __syncthreads();

    const float bdv = bd[tid], btv = bt[tid];
    float accd[8], acct[8];
    #pragma unroll
    for (int r = 0; r < 8; ++r) { accd[r] = bdv; acct[r] = btv; }

    for (int k = 0; k < DD; ++k) {
        const float wd = Wd[k * DD + tid];
        const float wt = Wt[k * DD + tid];
        #pragma unroll
        for (int r = 0; r < 8; ++r) {
            accd[r] += det_s[r][k] * wd;
            acct[r] += det_s[r][k] * wt;
        }
    }

    #pragma unroll
    for (int r = 0; r < 8; ++r) {
        obj[(row0 + r) * DD + tid]    = accd[r];
        trk_nb[(row0 + r) * DD + tid] = acct[r];
    }

    if (blockIdx.x == 0) {
        // reduce W_rel rows and b_rel across the 128 threads (2 waves)
        float v0 = Wr[tid];
        float v1 = Wr[DD + tid];
        float v2 = Wr[2 * DD + tid];
        float v3 = br[tid];
        #pragma unroll
        for (int off = 32; off > 0; off >>= 1) {
            v0 += __shfl_down(v0, off);
            v1 += __shfl_down(v1, off);
            v2 += __shfl_down(v2, off);
            v3 += __shfl_down(v3, off);
        }
        __shared__ float red[2][4];
        if ((tid & 63) == 0) {
            const int w = tid >> 6;
            red[w][0] = v0; red[w][1] = v1; red[w][2] = v2; red[w][3] = v3;
        }
        __syncthreads();
        if (tid == 0) {
            wsum[0] = red[0][0] + red[1][0];
            wsum[1] = red[0][1] + red[1][1];
            wsum[2] = red[0][2] + red[1][2];
            wsum[3] = red[0][3] + red[1][3];   // bsum
        }
    }
}

// ---------------------------------------------------------------------------
// Kernel B: det2track[n,m] = (obj[n].trk[m] + rel[n,m,:].wsum + bsum)/sqrt(D)
// Tile: 32 (n) x 64 (m) per block, 2x4 outputs per thread.
// LDS rows padded to 132 floats: row stride = 33 float4-chunks == 1 (mod 8)
// -> strided-row reads alias at most 2-way on banks (free).
// ---------------------------------------------------------------------------
#define TM 64
#define TN 32
#define LDSP 132

__global__ __launch_bounds__(256) void fuse_kernel(
    const float* __restrict__ obj, const float* __restrict__ trk,
    const float* __restrict__ rel, const float* __restrict__ wsum,
    float* __restrict__ out)
{
    const int t  = threadIdx.x;
    const int tx = t & 15;    // j base (m)
    const int ty = t >> 4;    // i base (n), 0..15
    const int m0 = blockIdx.x * TM;
    const int n0 = blockIdx.y * TN;

    __shared__ float obj_s[TN][LDSP];
    __shared__ float trk_s[TM][LDSP];

    // cooperative float4 loads: obj tile TN*32 chunks, trk tile TM*32 chunks
    #pragma unroll
    for (int idx = t; idx < TN * 32; idx += 256) {
        const int r = idx >> 5, c = idx & 31;
        const float4 v = reinterpret_cast<const float4*>(obj)[(n0 + r) * 32 + c];
        *reinterpret_cast<float4*>(&obj_s[r][c * 4]) = v;
    }
    #pragma unroll
    for (int idx = t; idx < TM * 32; idx += 256) {
        const int r = idx >> 5, c = idx & 31;
        const float4 v = reinterpret_cast<const float4*>(trk)[(m0 + r) * 32 + c];
        *reinterpret_cast<float4*>(&trk_s[r][c * 4]) = v;
    }

    const float w0 = wsum[0], w1 = wsum[1], w2 = wsum[2], bsum = wsum[3];
    __syncthreads();

    float acc[2][4];
    #pragma unroll
    for (int di = 0; di < 2; ++di) {
        #pragma unroll
        for (int dj = 0; dj < 4; ++dj) {
            const int n = n0 + ty + 16 * di;
            const int m = m0 + tx + 16 * dj;
            const float* rp = rel + ((size_t)n * N_TRK + m) * RR;
            acc[di][dj] = bsum + rp[0] * w0 + rp[1] * w1 + rp[2] * w2;
        }
    }

    for (int k4 = 0; k4 < DD / 4; ++k4) {
        float4 a[2], b[4];
        #pragma unroll
        for (int di = 0; di < 2; ++di)
            a[di] = *reinterpret_cast<const float4*>(&obj_s[ty + 16 * di][k4 * 4]);
        #pragma unroll
        for (int dj = 0; dj < 4; ++dj)
            b[dj] = *reinterpret_cast<const float4*>(&trk_s[tx + 16 * dj][k4 * 4]);
        #pragma unroll
        for (int di = 0; di < 2; ++di) {
            #pragma unroll
            for (int dj = 0; dj < 4; ++dj) {
                acc[di][dj] += a[di].x * b[dj].x + a[di].y * b[dj].y
                             + a[di].z * b[dj].z + a[di].w * b[dj].w;
            }
        }
    }

    const float inv = 0.08838834764831845f;  // 1/sqrt(128)
    #pragma unroll
    for (int di = 0; di < 2; ++di) {
        #pragma unroll
        for (int dj = 0; dj < 4; ++dj) {
            const int n = n0 + ty + 16 * di;
            const int m = m0 + tx + 16 * dj;
            out[(size_t)n * N_TRK + m] = acc[di][dj] * inv;
        }
    }
}

extern "C" void kernel_launch(void* const* d_in, const int* in_sizes, int n_in,
                              void* d_out, int out_size, void* d_ws, size_t ws_size,
                              hipStream_t stream) {
    const float* det = (const float*)d_in[0];
    const float* trk = (const float*)d_in[1];
    const float* rel = (const float*)d_in[2];
    const float* Wd  = (const float*)d_in[3];
    const float* bd  = (const float*)d_in[4];
    const float* Wt  = (const float*)d_in[5];
    const float* bt  = (const float*)d_in[6];
    const float* Wr  = (const float*)d_in[7];
    const float* br  = (const float*)d_in[8];

    float* out_mat = (float*)d_out;                        // [N_DET, N_TRK]
    float* out_trk = out_mat + (size_t)N_DET * N_TRK;      // [N_DET, D]

    float* obj  = (float*)d_ws;                            // [N_DET, D]
    float* wsum = obj + (size_t)N_DET * DD;                // [4]

    linears_kernel<<<N_DET / 8, 128, 0, stream>>>(
        det, Wd, bd, Wt, bt, Wr, br, obj, out_trk, wsum);

    fuse_kernel<<<dim3(N_TRK / TM, N_DET / TN), 256, 0, stream>>>(
        obj, trk, rel, wsum, out_mat);
}

// Round 2
// 16.293 us; speedup vs baseline: 1.4273x; 1.4273x over previous
//
#include <hip/hip_runtime.h>
#include <hip/hip_bf16.h>

#define N_DET 1024
#define N_TRK 1024
#define DD 128
#define RR 3

typedef __attribute__((ext_vector_type(8))) short short8;
typedef __attribute__((ext_vector_type(4))) float f32x4;

// ---------------------------------------------------------------------------
// Kernel A (prep): 256 blocks x 256 threads, 4 det rows per block, k-split 2.
//   objb    = bf16(det @ W_det + b_det)            -> ws
//   trk_nb  = det @ W_trk + b_trk (exact f32)      -> d_out tail
//   trkb    = bf16(track_embedding)                -> ws
//   wsum[r] = sum_d W_rel[r][d], bsum = sum_d b_rel[d]  (block 0, wave 0)
// ---------------------------------------------------------------------------
__global__ __launch_bounds__(256) void prep_kernel(
    const float* __restrict__ det, const float* __restrict__ trk,
    const float* __restrict__ Wd, const float* __restrict__ bd,
    const float* __restrict__ Wt, const float* __restrict__ bt,
    const float* __restrict__ Wr, const float* __restrict__ br,
    __hip_bfloat16* __restrict__ objb, __hip_bfloat16* __restrict__ trkb,
    float* __restrict__ trk_nb, float* __restrict__ wsum)
{
    const int tid  = threadIdx.x;
    const int col  = tid & 127;
    const int half = tid >> 7;          // which k-half (0: k<64, 1: k>=64)
    const int row0 = blockIdx.x * 4;

    __shared__ float det_s[4][DD];
    __shared__ float partd[4][DD];
    __shared__ float partt[4][DD];

    #pragma unroll
    for (int i = 0; i < 2; ++i) {
        const int e = tid + i * 256;
        det_s[e >> 7][e & 127] = det[row0 * DD + e];
    }
    __syncthreads();

    float ad[4] = {0.f, 0.f, 0.f, 0.f};
    float at[4] = {0.f, 0.f, 0.f, 0.f};
    const int kbase = half * 64;
    #pragma unroll 4
    for (int k = 0; k < 64; ++k) {
        const int kk = kbase + k;
        const float wd = Wd[kk * DD + col];
        const float wt = Wt[kk * DD + col];
        #pragma unroll
        for (int r = 0; r < 4; ++r) {
            ad[r] = fmaf(det_s[r][kk], wd, ad[r]);
            at[r] = fmaf(det_s[r][kk], wt, at[r]);
        }
    }

    if (half == 1) {
        #pragma unroll
        for (int r = 0; r < 4; ++r) { partd[r][col] = ad[r]; partt[r][col] = at[r]; }
    }
    __syncthreads();

    if (half == 0) {
        const float bdv = bd[col], btv = bt[col];
        #pragma unroll
        for (int r = 0; r < 4; ++r) {
            const float od = ad[r] + partd[r][col] + bdv;
            const float ot = at[r] + partt[r][col] + btv;
            objb[(row0 + r) * DD + col]   = __float2bfloat16(od);
            trk_nb[(row0 + r) * DD + col] = ot;
        }
    } else {
        // cast 4 track rows to bf16 (threads 128..255, 4 elems each)
        #pragma unroll
        for (int i = 0; i < 4; ++i) {
            const int e = col + i * 128;
            trkb[row0 * DD + e] = __float2bfloat16(trk[row0 * DD + e]);
        }
    }

    if (blockIdx.x == 0 && tid < 64) {
        float v0 = Wr[tid]          + Wr[64 + tid];
        float v1 = Wr[DD + tid]     + Wr[DD + 64 + tid];
        float v2 = Wr[2 * DD + tid] + Wr[2 * DD + 64 + tid];
        float v3 = br[tid]          + br[64 + tid];
        #pragma unroll
        for (int off = 32; off > 0; off >>= 1) {
            v0 += __shfl_down(v0, off);
            v1 += __shfl_down(v1, off);
            v2 += __shfl_down(v2, off);
            v3 += __shfl_down(v3, off);
        }
        if (tid == 0) { wsum[0] = v0; wsum[1] = v1; wsum[2] = v2; wsum[3] = v3; }
    }
}

// ---------------------------------------------------------------------------
// Kernel B (fuse): one 16x16 output tile per wave via mfma_f32_16x16x32_bf16.
// Block = 4 waves covering n:16 x m:64. Grid (1024/64, 1024/16) = 16 x 64.
// A frag: lane l holds obj[n0 + (l&15)][ks*32 + 8*(l>>4) + b], b=0..7 (16B).
// B frag: lane l holds trk[m0 + (l&15)][same k]  (B[k][col] = trk[col][k]).
// C/D:    col = l&15, row = (l>>4)*4 + reg   [m89-verified].
// Epilogue folds rel_dist dot wsum + bsum, all scaled by 1/sqrt(D).
// ---------------------------------------------------------------------------
__global__ __launch_bounds__(256) void fuse_mfma_kernel(
    const __hip_bfloat16* __restrict__ objb,
    const __hip_bfloat16* __restrict__ trkb,
    const float* __restrict__ rel, const float* __restrict__ wsum,
    float* __restrict__ out)
{
    const int t    = threadIdx.x;
    const int wave = t >> 6;
    const int l    = t & 63;
    const int lq   = l >> 4;                    // 0..3
    const int lr   = l & 15;
    const int n0   = blockIdx.y * 16;
    const int m0   = blockIdx.x * 64 + wave * 16;

    const float inv = 0.08838834764831845f;     // 1/sqrt(128)
    const float w0 = wsum[0] * inv, w1 = wsum[1] * inv;
    const float w2 = wsum[2] * inv, bs = wsum[3] * inv;

    const short8* ap = reinterpret_cast<const short8*>(objb + (n0 + lr) * DD + lq * 8);
    const short8* bp = reinterpret_cast<const short8*>(trkb + (m0 + lr) * DD + lq * 8);

    f32x4 acc = {0.f, 0.f, 0.f, 0.f};
    #pragma unroll
    for (int ks = 0; ks < 4; ++ks) {
        const short8 a = ap[ks * 4];            // +32 elements per K-step
        const short8 b = bp[ks * 4];
        acc = __builtin_amdgcn_mfma_f32_16x16x32_bf16(a, b, acc, 0, 0, 0);
    }

    #pragma unroll
    for (int r = 0; r < 4; ++r) {
        const int n = n0 + lq * 4 + r;
        const int m = m0 + lr;
        const size_t ri = ((size_t)n * N_TRK + m) * RR;
        const float mo = bs + rel[ri] * w0 + rel[ri + 1] * w1 + rel[ri + 2] * w2;
        out[(size_t)n * N_TRK + m] = fmaf(acc[r], inv, mo);
    }
}

extern "C" void kernel_launch(void* const* d_in, const int* in_sizes, int n_in,
                              void* d_out, int out_size, void* d_ws, size_t ws_size,
                              hipStream_t stream) {
    const float* det = (const float*)d_in[0];
    const float* trk = (const float*)d_in[1];
    const float* rel = (const float*)d_in[2];
    const float* Wd  = (const float*)d_in[3];
    const float* bd  = (const float*)d_in[4];
    const float* Wt  = (const float*)d_in[5];
    const float* bt  = (const float*)d_in[6];
    const float* Wr  = (const float*)d_in[7];
    const float* br  = (const float*)d_in[8];

    float* out_mat = (float*)d_out;                        // [N_DET, N_TRK]
    float* out_trk = out_mat + (size_t)N_DET * N_TRK;      // [N_DET, D]

    __hip_bfloat16* objb = (__hip_bfloat16*)d_ws;          // [N_DET, D] bf16
    __hip_bfloat16* trkb = objb + (size_t)N_DET * DD;      // [N_TRK, D] bf16
    float* wsum = (float*)(trkb + (size_t)N_TRK * DD);     // [4]

    prep_kernel<<<N_DET / 4, 256, 0, stream>>>(
        det, trk, Wd, bd, Wt, bt, Wr, br, objb, trkb, out_trk, wsum);

    fuse_mfma_kernel<<<dim3(N_TRK / 64, N_DET / 16), 256, 0, stream>>>(
        objb, trkb, rel, wsum, out_mat);
}